// Round 19
// baseline (689.370 us; speedup 1.0000x reference)
//
#include <hip/hip_runtime.h>
#include <math.h>

#define N_TOK 8192
#define C_DIM 1024
#define D_DIM 3072
#define E_NUM 8
#define SEG 128
#define MAXB 136   // sum ceil(cnt_e/128) <= 128 + 8; MAXB % 4 == 0

typedef unsigned short u16;
typedef unsigned int u32;
typedef __attribute__((ext_vector_type(8))) short bf16x8;
typedef __attribute__((ext_vector_type(4))) float f32x4;

__device__ __forceinline__ u16 f2bf(float f) {
  u32 u = __builtin_bit_cast(unsigned int, f);
  u = (u + 0x7FFFu + ((u >> 16) & 1u)) >> 16;
  return (u16)u;
}

__device__ __forceinline__ void gl_lds16(const void* g, void* l) {
  __builtin_amdgcn_global_load_lds(
      (const __attribute__((address_space(1))) unsigned int*)g,
      (__attribute__((address_space(3))) unsigned int*)l, 16, 0, 0);
}

// ---------------- micro-init: counters + out tail (aux loss) ----------------
__global__ void zcnt_kernel(float* __restrict__ out, int n, int* __restrict__ cnt) {
  if (threadIdx.x < E_NUM) cnt[threadIdx.x] = 0;
  const int tail = n & 3;
  if (threadIdx.x < tail) out[n - 1 - (int)threadIdx.x] = 0.0f;
}

// ---------------- router (+ zero own out rows): logits fp64, top-2, scatter ----------------
__global__ void router_kernel(const float* __restrict__ x, const float* __restrict__ rw,
                              int* __restrict__ cnt, int* __restrict__ list,
                              float* __restrict__ wl, float* __restrict__ out) {
  const int lane = threadIdx.x & 63;
  const int n = blockIdx.x * 4 + (threadIdx.x >> 6);
  {
    float4 z = make_float4(0.f, 0.f, 0.f, 0.f);
    float* orow = out + (size_t)n * C_DIM;
#pragma unroll
    for (int i = 0; i < 4; i++) *(float4*)(orow + lane * 4 + i * 256) = z;
  }
  const float* xr = x + (size_t)n * C_DIM;
  double acc[E_NUM];
#pragma unroll
  for (int e = 0; e < E_NUM; e++) acc[e] = 0.0;
#pragma unroll
  for (int i = 0; i < 4; i++) {
    const int c = lane * 4 + i * 256;
    float4 xv = *(const float4*)(xr + c);
#pragma unroll
    for (int e = 0; e < E_NUM; e++) {
      const float* rwe = rw + e * C_DIM + c;
      acc[e] += (double)xv.x * (double)rwe[0] + (double)xv.y * (double)rwe[1]
              + (double)xv.z * (double)rwe[2] + (double)xv.w * (double)rwe[3];
    }
  }
#pragma unroll
  for (int e = 0; e < E_NUM; e++) {
    double v = acc[e];
#pragma unroll
    for (int off = 32; off > 0; off >>= 1) v += __shfl_down(v, off, 64);
    acc[e] = v;
  }
  if (lane == 0) {
    int i0 = 0;
#pragma unroll
    for (int e = 1; e < E_NUM; e++) if (acc[e] > acc[i0]) i0 = e;
    int i1 = (i0 == 0) ? 1 : 0;
#pragma unroll
    for (int e = 0; e < E_NUM; e++) if (e != i0 && acc[e] > acc[i1]) i1 = e;
    double d = acc[i0] - acc[i1];          // >= 0
    double w0 = 1.0 / (1.0 + exp(-d));     // p0/(p0+p1)
    double w1 = 1.0 - w0;
    int p0 = atomicAdd(&cnt[i0], 1);
    list[i0 * N_TOK + p0] = n; wl[i0 * N_TOK + p0] = (float)w0;
    int p1 = atomicAdd(&cnt[i1], 1);
    list[i1 * N_TOK + p1] = n; wl[i1 * N_TOK + p1] = (float)w1;
  }
}

// -------- transpose+convert: in [E][R][CC] f32 -> out [E][CC][R] bf16 --------
template<int R, int CC>
__global__ __launch_bounds__(512) void transpose_conv_kernel(
    const float* __restrict__ in, u16* __restrict__ outp) {
  __shared__ float t[32][257];
  const int e = blockIdx.z;
  const int r0 = blockIdx.y * 32;
  const int c0 = blockIdx.x * 256;
  const int tid = threadIdx.x;
  const int lr = tid >> 6;
  const int lc = (tid & 63) * 4;
#pragma unroll
  for (int i = 0; i < 4; i++) {
    const int rr = lr + i * 8;
    float4 v = *(const float4*)(in + ((size_t)e * R + r0 + rr) * CC + c0 + lc);
    t[rr][lc] = v.x; t[rr][lc + 1] = v.y; t[rr][lc + 2] = v.z; t[rr][lc + 3] = v.w;
  }
  __syncthreads();
  const int od = tid >> 1;
  const int seg = (tid & 1) * 16;
  union { u16 s[16]; uint4 v[2]; } o;
#pragma unroll
  for (int j = 0; j < 16; j++) o.s[j] = f2bf(t[seg + j][od]);
  u16* dst = outp + ((size_t)e * CC + c0 + od) * R + r0 + seg;
  *(uint4*)(dst) = o.v[0];
  *(uint4*)(dst + 8) = o.v[1];
}

// ---------------- prefix sum + block table (PARALLEL: 64 lanes) ----------------
__global__ void prefix_kernel(const int* __restrict__ cnt, int* __restrict__ rowbase,
                              int* __restrict__ btab) {
  const int lane = threadIdx.x;
  int c[E_NUM], rbse[E_NUM], nseg[E_NUM], nsb[E_NUM];
  int s = 0, t = 0;
#pragma unroll
  for (int e = 0; e < E_NUM; e++) {
    c[e] = cnt[e]; rbse[e] = s; s += c[e];
    nseg[e] = (c[e] + SEG - 1) / SEG; nsb[e] = t; t += nseg[e];
  }
  if (lane < E_NUM) rowbase[lane] = rbse[lane];
  for (int i = lane; i < MAXB; i += 64) {
    int e = -1, m0 = 0;
#pragma unroll
    for (int k = 0; k < E_NUM; k++)
      if (i >= nsb[k] && i < nsb[k] + nseg[k]) { e = k; m0 = (i - nsb[k]) * SEG; }
    btab[2 * i] = e; btab[2 * i + 1] = m0;
  }
}

// ------- gather + convert (flat-row): Xg[r] = bf16(x[list[e][r-rowbase[e]]]) -------
__global__ void gather_x_kernel(const float* __restrict__ x, const int* __restrict__ rowbase,
                                const int* __restrict__ list, u16* __restrict__ Xg) {
  const int rflat = blockIdx.x * 4 + (threadIdx.x >> 6);
  const int lane = threadIdx.x & 63;
  int e = E_NUM - 1;
#pragma unroll
  for (int k = 1; k < E_NUM; k++) if (rflat < rowbase[k]) { e = k - 1; break; }
  const int p = rflat - rowbase[e];
  const int tok = list[e * N_TOK + p];
  const float* src = x + (size_t)tok * C_DIM;
  u16* dst = Xg + (size_t)rflat * C_DIM;
#pragma unroll
  for (int i = 0; i < 4; i++) {
    float4 v = *(const float4*)(src + lane * 4 + i * 256);
    ushort4 o;
    o.x = f2bf(v.x); o.y = f2bf(v.y); o.z = f2bf(v.z); o.w = f2bf(v.w);
    *(ushort4*)(dst + lane * 4 + i * 256) = o;
  }
}

// ---- 128x128 tile, 256 thr, gl_lds 3-SLOT RING (48KB -> 3 blk/CU), depth-2 ----
// The untested cell of {depth x blocks/CU}: counted vmcnt keeps 2 stages in
// flight ACROSS barriers (never drains to 0 in the loop) while 3 co-resident
// blocks provide TLP cover. gl_lds staging -> no staging VGPRs -> no spill.
// EPI=1: h = gelu(Xg @ W1t^T + b1)     A=Xg dense rows, Wt=[E][D][C]
// EPI=2: out += w*(h @ W2t^T + b2)     A=h dense rows,  Wt=[E][C][D]
template<int NN0, int K, int EPI>
__global__ __launch_bounds__(256, 4) void gemm_d3_kernel(
    const u16* __restrict__ A, const u16* __restrict__ Wt, const float* __restrict__ bias_,
    const int* __restrict__ btab, const int* __restrict__ cnt, const int* __restrict__ rowbase,
    const int* __restrict__ list, const float* __restrict__ wl,
    u16* __restrict__ hout, float* __restrict__ out) {
  constexpr int NTOT = NN0 * 128;
  constexpr int NT = K / 32;       // K-steps (32 / 96)
  constexpr int NG = NN0 / 4;      // n0 cohort groups
  constexpr int TOT = MAXB * NN0;  // grid size (TOT % 8 == 0)

  __shared__ __align__(16) u16 ldsA[3 * 128 * 32];  // 24 KB: 3 slots
  __shared__ __align__(16) u16 ldsB[3 * 128 * 32];  // 24 KB

  const int L = (blockIdx.x & 7) * (TOT / 8) + (blockIdx.x >> 3);
  const int coh = L >> 4, r = L & 15;
  const int bxg = coh / NG;
  const int n0g = coh % NG;
  const int bx = bxg * 4 + (r & 3);
  const int n0 = (n0g * 4 + (r >> 2)) * 128;

  const int e = btab[bx * 2];
  if (e < 0) return;
  const int m0 = btab[bx * 2 + 1];
  const int count = cnt[e];
  const int rb = rowbase[e];

  const int tid = threadIdx.x;
  const int lane = tid & 63;
  const int wid = tid >> 6;
  const int wm = (wid >> 1) * 64;
  const int wn = (wid & 1) * 64;
  const int l15 = lane & 15, l4 = lane >> 4;

  // staging: row = tid>>2 (+64), 16B pos = (tid&3)*8 u16. LINEAR (coalesced).
  const int arow0 = tid >> 2, pos = (tid & 3) * 8;
  const u16* aptr0 = A + (size_t)(rb + min(m0 + arow0, count - 1)) * K + pos;
  const u16* aptr1 = A + (size_t)(rb + min(m0 + arow0 + 64, count - 1)) * K + pos;
  const u16* bptr0 = Wt + ((size_t)e * NTOT + n0 + arow0) * K + pos;
  const u16* bptr1 = Wt + ((size_t)e * NTOT + n0 + arow0 + 64) * K + pos;

  const int paoff = (wm + l15) * 32 + l4 * 8;
  const int pboff = (wn + l15) * 32 + l4 * 8;

  f32x4 acc[4][4];
#pragma unroll
  for (int i = 0; i < 4; i++)
#pragma unroll
    for (int j = 0; j < 4; j++) acc[i][j] = {0.f, 0.f, 0.f, 0.f};

  auto STAGE = [&](int t) {            // stage K-step t into slot t%3 (4 gl_lds)
    const int s = (t % 3) * 4096;
    const int ko = t * 32;
    gl_lds16(aptr0 + ko, ldsA + s + tid * 8);
    gl_lds16(aptr1 + ko, ldsA + s + 2048 + tid * 8);
    gl_lds16(bptr0 + ko, ldsB + s + tid * 8);
    gl_lds16(bptr1 + ko, ldsB + s + 2048 + tid * 8);
  };

  auto PHASE = [&](int t) {
    const int s = (t % 3) * 4096;
    const u16* pa = ldsA + s + paoff;
    const u16* pb = ldsB + s + pboff;
    bf16x8 av[4], bv[4];
#pragma unroll
    for (int i = 0; i < 4; i++) av[i] = *(const bf16x8*)(pa + i * 512);
#pragma unroll
    for (int j = 0; j < 4; j++) bv[j] = *(const bf16x8*)(pb + j * 512);
#pragma unroll
    for (int i = 0; i < 4; i++)
#pragma unroll
      for (int j = 0; j < 4; j++)
        acc[i][j] = __builtin_amdgcn_mfma_f32_16x16x32_bf16(av[i], bv[j], acc[i][j], 0, 0, 0);
  };

  // prologue: 2 stages in flight
  STAGE(0); STAGE(1);
  for (int t = 0; t < NT - 2; ++t) {
    STAGE(t + 2);                        // overwrites slot (t-1)%3: released by
                                         // the end-barrier of iteration t-1
    asm volatile("s_waitcnt vmcnt(8)");  // stage t landed; t+1, t+2 stay in flight
    __builtin_amdgcn_sched_barrier(0);
    __builtin_amdgcn_s_barrier();        // all waves: slot t%3 fully staged
    __builtin_amdgcn_sched_barrier(0);
    PHASE(t);
    __builtin_amdgcn_s_barrier();        // all waves done reading slot t%3
    __builtin_amdgcn_sched_barrier(0);
  }
  // tail: stages NT-2, NT-1 in flight (8 outstanding)
  asm volatile("s_waitcnt vmcnt(4)");    // stage NT-2 landed
  __builtin_amdgcn_sched_barrier(0);
  __builtin_amdgcn_s_barrier();
  __builtin_amdgcn_sched_barrier(0);
  PHASE(NT - 2);
  __builtin_amdgcn_s_barrier();
  __builtin_amdgcn_sched_barrier(0);
  asm volatile("s_waitcnt vmcnt(0)");    // stage NT-1 landed
  __builtin_amdgcn_sched_barrier(0);
  __builtin_amdgcn_s_barrier();
  __builtin_amdgcn_sched_barrier(0);
  PHASE(NT - 1);

  // ---------------- epilogue ----------------
  if constexpr (EPI == 1) {
#pragma unroll
    for (int i = 0; i < 4; i++) {
      const int rloc = wm + i * 16 + l4 * 4;
#pragma unroll
      for (int j = 0; j < 4; j++) {
        const int col = n0 + wn + j * 16 + l15;
        const float bias = bias_[e * NTOT + col];
#pragma unroll
        for (int rr = 0; rr < 4; rr++) {
          const int m = m0 + rloc + rr;
          if (m < count) {
            float v = acc[i][j][rr] + bias;
            float g = 0.5f * v * (1.0f + erff(v * 0.70710678118654752f));
            hout[(size_t)(rb + m) * D_DIM + col] = f2bf(g);
          }
        }
      }
    }
  } else {
    const int* lst = list + e * N_TOK;
    const float* wlst = wl + e * N_TOK;
#pragma unroll
    for (int i = 0; i < 4; i++) {
      const int rloc = wm + i * 16 + l4 * 4;
#pragma unroll
      for (int j = 0; j < 4; j++) {
        const int col = n0 + wn + j * 16 + l15;
        const float bias = bias_[e * NTOT + col];
#pragma unroll
        for (int rr = 0; rr < 4; rr++) {
          const int m = m0 + rloc + rr;
          if (m < count) {
            const int tk = lst[m];
            atomicAdd(out + (size_t)tk * C_DIM + col, wlst[m] * (acc[i][j][rr] + bias));
          }
        }
      }
    }
  }
}

extern "C" void kernel_launch(void* const* d_in, const int* in_sizes, int n_in,
                              void* d_out, int out_size, void* d_ws, size_t ws_size,
                              hipStream_t stream) {
  const float* x  = (const float*)d_in[0];
  const float* rw = (const float*)d_in[1];
  const float* W1 = (const float*)d_in[2];
  const float* b1 = (const float*)d_in[3];
  const float* W2 = (const float*)d_in[4];
  const float* b2 = (const float*)d_in[5];
  float* out = (float*)d_out;

  char* ws = (char*)d_ws;
  u16* W1t    = (u16*)(ws);                      // 50,331,648 B
  u16* Xg     = (u16*)(ws + 50331648);           // 33,554,432 B (overlaid by W2t after gemm1)
  u16* W2t    = (u16*)(ws + 50331648);           // 50,331,648 B (written AFTER gemm1)
  int* cnt    = (int*)(ws + 100663296);          // 256 B
  int* rowbase= (int*)(ws + 100663552);          // 256 B
  int* list   = (int*)(ws + 100663808);          // 262,144 B
  float* wl   = (float*)(ws + 100925952);        // 262,144 B
  int* btab   = (int*)(ws + 101188096);          // 2,048 B
  u16* h      = (u16*)(ws + 101190656);          // 100,663,296 B -> end 201,853,952

  zcnt_kernel<<<1, 64, 0, stream>>>(out, out_size, cnt);
  router_kernel<<<N_TOK / 4, 256, 0, stream>>>(x, rw, cnt, list, wl, out);
  prefix_kernel<<<1, 64, 0, stream>>>(cnt, rowbase, btab);
  gather_x_kernel<<<(2 * N_TOK) / 4, 256, 0, stream>>>(x, rowbase, list, Xg);
  // W1 [E][C][D] f32 -> W1t [E][D][C] bf16
  transpose_conv_kernel<C_DIM, D_DIM><<<dim3(D_DIM / 256, C_DIM / 32, E_NUM), 512, 0, stream>>>(W1, W1t);
  gemm_d3_kernel<24, C_DIM, 1><<<MAXB * 24, 256, 0, stream>>>(
      Xg, W1t, b1, btab, cnt, rowbase, list, wl, h, out);
  // W2 [E][D][C] f32 -> W2t [E][C][D] bf16
  transpose_conv_kernel<D_DIM, C_DIM><<<dim3(C_DIM / 256, D_DIM / 32, E_NUM), 512, 0, stream>>>(W2, W2t);
  gemm_d3_kernel<8, D_DIM, 2><<<MAXB * 8, 256, 0, stream>>>(
      h, W2t, b2, btab, cnt, rowbase, list, wl, h, out);
}

// Round 20
// 653.658 us; speedup vs baseline: 1.0546x; 1.0546x over previous
//
#include <hip/hip_runtime.h>
#include <math.h>

#define N_TOK 8192
#define C_DIM 1024
#define D_DIM 3072
#define E_NUM 8
#define SEG 128
#define MAXB 136   // sum ceil(cnt_e/128) <= 128 + 8; MAXB % 4 == 0

typedef unsigned short u16;
typedef unsigned int u32;
typedef __attribute__((ext_vector_type(8))) short bf16x8;
typedef __attribute__((ext_vector_type(4))) float f32x4;

__device__ __forceinline__ u16 f2bf(float f) {
  u32 u = __builtin_bit_cast(unsigned int, f);
  u = (u + 0x7FFFu + ((u >> 16) & 1u)) >> 16;
  return (u16)u;
}

// ---------------- micro-init: counters + out tail (aux loss) ----------------
__global__ void zcnt_kernel(float* __restrict__ out, int n, int* __restrict__ cnt) {
  if (threadIdx.x < E_NUM) cnt[threadIdx.x] = 0;
  const int tail = n & 3;                 // elems beyond the router-zeroed 4-row grid
  if (threadIdx.x < tail) out[n - 1 - (int)threadIdx.x] = 0.0f;
}

// ---------------- router (+ zero own out rows): logits fp64, top-2, scatter ----------------
__global__ void router_kernel(const float* __restrict__ x, const float* __restrict__ rw,
                              int* __restrict__ cnt, int* __restrict__ list,
                              float* __restrict__ wl, float* __restrict__ out) {
  const int lane = threadIdx.x & 63;
  const int n = blockIdx.x * 4 + (threadIdx.x >> 6);
  // zero this token's output row (untouched until gemm2's atomics -- safe)
  {
    float4 z = make_float4(0.f, 0.f, 0.f, 0.f);
    float* orow = out + (size_t)n * C_DIM;
#pragma unroll
    for (int i = 0; i < 4; i++) *(float4*)(orow + lane * 4 + i * 256) = z;
  }
  const float* xr = x + (size_t)n * C_DIM;
  double acc[E_NUM];
#pragma unroll
  for (int e = 0; e < E_NUM; e++) acc[e] = 0.0;
#pragma unroll
  for (int i = 0; i < 4; i++) {
    const int c = lane * 4 + i * 256;
    float4 xv = *(const float4*)(xr + c);
#pragma unroll
    for (int e = 0; e < E_NUM; e++) {
      const float* rwe = rw + e * C_DIM + c;
      acc[e] += (double)xv.x * (double)rwe[0] + (double)xv.y * (double)rwe[1]
              + (double)xv.z * (double)rwe[2] + (double)xv.w * (double)rwe[3];
    }
  }
#pragma unroll
  for (int e = 0; e < E_NUM; e++) {
    double v = acc[e];
#pragma unroll
    for (int off = 32; off > 0; off >>= 1) v += __shfl_down(v, off, 64);
    acc[e] = v;
  }
  if (lane == 0) {
    int i0 = 0;
#pragma unroll
    for (int e = 1; e < E_NUM; e++) if (acc[e] > acc[i0]) i0 = e;
    int i1 = (i0 == 0) ? 1 : 0;
#pragma unroll
    for (int e = 0; e < E_NUM; e++) if (e != i0 && acc[e] > acc[i1]) i1 = e;
    double d = acc[i0] - acc[i1];          // >= 0
    double w0 = 1.0 / (1.0 + exp(-d));     // p0/(p0+p1)
    double w1 = 1.0 - w0;
    int p0 = atomicAdd(&cnt[i0], 1);
    list[i0 * N_TOK + p0] = n; wl[i0 * N_TOK + p0] = (float)w0;
    int p1 = atomicAdd(&cnt[i1], 1);
    list[i1 * N_TOK + p1] = n; wl[i1 * N_TOK + p1] = (float)w1;
  }
}

// -------- transpose+convert: in [E][R][CC] f32 -> out [E][CC][R] bf16 --------
// 512 thr; input tile 32 rows x 256 cols; pad-257 LDS (strided reads conflict-free).
template<int R, int CC>
__global__ __launch_bounds__(512) void transpose_conv_kernel(
    const float* __restrict__ in, u16* __restrict__ outp) {
  __shared__ float t[32][257];
  const int e = blockIdx.z;
  const int r0 = blockIdx.y * 32;   // input-row tile base (K dim of output)
  const int c0 = blockIdx.x * 256;  // input-col tile base (row dim of output)
  const int tid = threadIdx.x;
  const int lr = tid >> 6;          // 0..7
  const int lc = (tid & 63) * 4;    // 0..252
#pragma unroll
  for (int i = 0; i < 4; i++) {
    const int rr = lr + i * 8;
    float4 v = *(const float4*)(in + ((size_t)e * R + r0 + rr) * CC + c0 + lc);
    t[rr][lc] = v.x; t[rr][lc + 1] = v.y; t[rr][lc + 2] = v.z; t[rr][lc + 3] = v.w;
  }
  __syncthreads();
  const int od = tid >> 1;
  const int seg = (tid & 1) * 16;
  union { u16 s[16]; uint4 v[2]; } o;
#pragma unroll
  for (int j = 0; j < 16; j++) o.s[j] = f2bf(t[seg + j][od]);
  u16* dst = outp + ((size_t)e * CC + c0 + od) * R + r0 + seg;
  *(uint4*)(dst) = o.v[0];
  *(uint4*)(dst + 8) = o.v[1];
}

// ---------------- prefix sum + block table (PARALLEL: 64 lanes) ----------------
__global__ void prefix_kernel(const int* __restrict__ cnt, int* __restrict__ rowbase,
                              int* __restrict__ btab) {
  const int lane = threadIdx.x;
  int c[E_NUM], rbse[E_NUM], nseg[E_NUM], nsb[E_NUM];
  int s = 0, t = 0;
#pragma unroll
  for (int e = 0; e < E_NUM; e++) {
    c[e] = cnt[e]; rbse[e] = s; s += c[e];
    nseg[e] = (c[e] + SEG - 1) / SEG; nsb[e] = t; t += nseg[e];
  }
  if (lane < E_NUM) rowbase[lane] = rbse[lane];
  for (int i = lane; i < MAXB; i += 64) {
    int e = -1, m0 = 0;
#pragma unroll
    for (int k = 0; k < E_NUM; k++)
      if (i >= nsb[k] && i < nsb[k] + nseg[k]) { e = k; m0 = (i - nsb[k]) * SEG; }
    btab[2 * i] = e; btab[2 * i + 1] = m0;
  }
}

// ------- gather + convert (flat-row): Xg[r] = bf16(x[list[e][r-rowbase[e]]]) -------
__global__ void gather_x_kernel(const float* __restrict__ x, const int* __restrict__ rowbase,
                                const int* __restrict__ list, u16* __restrict__ Xg) {
  const int rflat = blockIdx.x * 4 + (threadIdx.x >> 6);   // 0 .. 2*N_TOK-1
  const int lane = threadIdx.x & 63;
  int e = E_NUM - 1;
#pragma unroll
  for (int k = 1; k < E_NUM; k++) if (rflat < rowbase[k]) { e = k - 1; break; }
  const int p = rflat - rowbase[e];
  const int tok = list[e * N_TOK + p];
  const float* src = x + (size_t)tok * C_DIM;
  u16* dst = Xg + (size_t)rflat * C_DIM;
#pragma unroll
  for (int i = 0; i < 4; i++) {
    float4 v = *(const float4*)(src + lane * 4 + i * 256);
    ushort4 o;
    o.x = f2bf(v.x); o.y = f2bf(v.y); o.z = f2bf(v.z); o.w = f2bf(v.w);
    *(ushort4*)(dst + lane * 4 + i * 256) = o;
  }
}

// ---- 128x128 tile, 256 threads, 4 blocks/CU, REG-STAGED (R13 verbatim) ----
// Best measured across 19 rounds: 229 us/GEMM (~450 TF), 7.3 TB/s staged delivery.
// EPI=1: h = gelu(Xg @ W1t^T + b1)     A=Xg dense rows, Wt=[E][D][C]
// EPI=2: out += w*(h @ W2t^T + b2)     A=h dense rows,  Wt=[E][C][D]
template<int NN0, int K, int EPI>
__global__ __launch_bounds__(256, 4) void gemm_rs_kernel(
    const u16* __restrict__ A, const u16* __restrict__ Wt, const float* __restrict__ bias_,
    const int* __restrict__ btab, const int* __restrict__ cnt, const int* __restrict__ rowbase,
    const int* __restrict__ list, const float* __restrict__ wl,
    u16* __restrict__ hout, float* __restrict__ out) {
  constexpr int NTOT = NN0 * 128;
  constexpr int NT = K / 32;       // K-steps
  constexpr int NG = NN0 / 4;      // n0 cohort groups
  constexpr int TOT = MAXB * NN0;  // grid size (TOT % 8 == 0)

  __shared__ __align__(16) u16 ldsA[2 * 128 * 32];  // 16 KB
  __shared__ __align__(16) u16 ldsB[2 * 128 * 32];  // 16 KB

  const int L = (blockIdx.x & 7) * (TOT / 8) + (blockIdx.x >> 3);
  const int coh = L >> 4, r = L & 15;
  const int bxg = coh / NG;
  const int n0g = coh % NG;
  const int bx = bxg * 4 + (r & 3);
  const int n0 = (n0g * 4 + (r >> 2)) * 128;

  const int e = btab[bx * 2];
  if (e < 0) return;
  const int m0 = btab[bx * 2 + 1];
  const int count = cnt[e];
  const int rb = rowbase[e];

  const int tid = threadIdx.x;
  const int lane = tid & 63;
  const int wid = tid >> 6;
  const int wm = (wid >> 1) * 64;
  const int wn = (wid & 1) * 64;
  const int l15 = lane & 15, l4 = lane >> 4;

  const int arow0 = tid >> 2, pos = (tid & 3) * 8;
  const u16* aptr0 = A + (size_t)(rb + min(m0 + arow0, count - 1)) * K + pos;
  const u16* aptr1 = A + (size_t)(rb + min(m0 + arow0 + 64, count - 1)) * K + pos;
  const u16* bptr0 = Wt + ((size_t)e * NTOT + n0 + arow0) * K + pos;
  const u16* bptr1 = Wt + ((size_t)e * NTOT + n0 + arow0 + 64) * K + pos;

  const int paoff = (wm + l15) * 32 + l4 * 8;
  const int pboff = (wn + l15) * 32 + l4 * 8;

  f32x4 acc[4][4];
#pragma unroll
  for (int i = 0; i < 4; i++)
#pragma unroll
    for (int j = 0; j < 4; j++) acc[i][j] = {0.f, 0.f, 0.f, 0.f};

  uint4 ra0, ra1, rb0, rb1;                 // in-flight staging registers
  auto LOAD = [&](int t) {
    const int ko = t * 32;
    ra0 = *(const uint4*)(aptr0 + ko);
    ra1 = *(const uint4*)(aptr1 + ko);
    rb0 = *(const uint4*)(bptr0 + ko);
    rb1 = *(const uint4*)(bptr1 + ko);
  };
  auto WRITE = [&](int b) {                  // compiler inserts counted vmcnt waits
    *(uint4*)(ldsA + b * 4096 + tid * 8) = ra0;
    *(uint4*)(ldsA + b * 4096 + 2048 + tid * 8) = ra1;
    *(uint4*)(ldsB + b * 4096 + tid * 8) = rb0;
    *(uint4*)(ldsB + b * 4096 + 2048 + tid * 8) = rb1;
  };

  auto PHASE = [&](int b) {
    const u16* pa = ldsA + b * 4096 + paoff;
    const u16* pb = ldsB + b * 4096 + pboff;
    bf16x8 av[4], bv[4];
#pragma unroll
    for (int i = 0; i < 4; i++) av[i] = *(const bf16x8*)(pa + i * 512);
#pragma unroll
    for (int j = 0; j < 4; j++) bv[j] = *(const bf16x8*)(pb + j * 512);
#pragma unroll
    for (int i = 0; i < 4; i++)
#pragma unroll
      for (int j = 0; j < 4; j++)
        acc[i][j] = __builtin_amdgcn_mfma_f32_16x16x32_bf16(av[i], bv[j], acc[i][j], 0, 0, 0);
  };

  LOAD(0);
  WRITE(0);
  asm volatile("s_waitcnt lgkmcnt(0)");
  __builtin_amdgcn_sched_barrier(0);

  for (int t = 0; t < NT - 1; ++t) {
    LOAD(t + 1);                         // VMEM in flight; hidden under phase t
    __builtin_amdgcn_s_barrier();        // publish WRITE(t&1) to all waves
    __builtin_amdgcn_sched_barrier(0);
    PHASE(t & 1);
    __builtin_amdgcn_s_barrier();        // all waves done reading old buf
    WRITE((t + 1) & 1);                  // counted vmcnt auto-inserted here
    asm volatile("s_waitcnt lgkmcnt(0)");
    __builtin_amdgcn_sched_barrier(0);
  }
  __builtin_amdgcn_s_barrier();
  __builtin_amdgcn_sched_barrier(0);
  PHASE((NT - 1) & 1);

  // ---------------- epilogue ----------------
  if constexpr (EPI == 1) {
#pragma unroll
    for (int i = 0; i < 4; i++) {
      const int rloc = wm + i * 16 + l4 * 4;
#pragma unroll
      for (int j = 0; j < 4; j++) {
        const int col = n0 + wn + j * 16 + l15;
        const float bias = bias_[e * NTOT + col];
#pragma unroll
        for (int rr = 0; rr < 4; rr++) {
          const int m = m0 + rloc + rr;
          if (m < count) {
            float v = acc[i][j][rr] + bias;
            float g = 0.5f * v * (1.0f + erff(v * 0.70710678118654752f));
            hout[(size_t)(rb + m) * D_DIM + col] = f2bf(g);
          }
        }
      }
    }
  } else {
    const int* lst = list + e * N_TOK;
    const float* wlst = wl + e * N_TOK;
#pragma unroll
    for (int i = 0; i < 4; i++) {
      const int rloc = wm + i * 16 + l4 * 4;
#pragma unroll
      for (int j = 0; j < 4; j++) {
        const int col = n0 + wn + j * 16 + l15;
        const float bias = bias_[e * NTOT + col];
#pragma unroll
        for (int rr = 0; rr < 4; rr++) {
          const int m = m0 + rloc + rr;
          if (m < count) {
            const int tk = lst[m];
            atomicAdd(out + (size_t)tk * C_DIM + col, wlst[m] * (acc[i][j][rr] + bias));
          }
        }
      }
    }
  }
}

extern "C" void kernel_launch(void* const* d_in, const int* in_sizes, int n_in,
                              void* d_out, int out_size, void* d_ws, size_t ws_size,
                              hipStream_t stream) {
  const float* x  = (const float*)d_in[0];
  const float* rw = (const float*)d_in[1];
  const float* W1 = (const float*)d_in[2];
  const float* b1 = (const float*)d_in[3];
  const float* W2 = (const float*)d_in[4];
  const float* b2 = (const float*)d_in[5];
  float* out = (float*)d_out;

  char* ws = (char*)d_ws;
  u16* W1t    = (u16*)(ws);                      // 50,331,648 B
  u16* Xg     = (u16*)(ws + 50331648);           // 33,554,432 B (overlaid by W2t after gemm1)
  u16* W2t    = (u16*)(ws + 50331648);           // 50,331,648 B (written AFTER gemm1)
  int* cnt    = (int*)(ws + 100663296);          // 256 B
  int* rowbase= (int*)(ws + 100663552);          // 256 B
  int* list   = (int*)(ws + 100663808);          // 262,144 B
  float* wl   = (float*)(ws + 100925952);        // 262,144 B
  int* btab   = (int*)(ws + 101188096);          // 2,048 B
  u16* h      = (u16*)(ws + 101190656);          // 100,663,296 B -> end 201,853,952

  zcnt_kernel<<<1, 64, 0, stream>>>(out, out_size, cnt);
  router_kernel<<<N_TOK / 4, 256, 0, stream>>>(x, rw, cnt, list, wl, out);
  prefix_kernel<<<1, 64, 0, stream>>>(cnt, rowbase, btab);
  gather_x_kernel<<<(2 * N_TOK) / 4, 256, 0, stream>>>(x, rowbase, list, Xg);
  // W1 [E][C][D] f32 -> W1t [E][D][C] bf16
  transpose_conv_kernel<C_DIM, D_DIM><<<dim3(D_DIM / 256, C_DIM / 32, E_NUM), 512, 0, stream>>>(W1, W1t);
  gemm_rs_kernel<24, C_DIM, 1><<<MAXB * 24, 256, 0, stream>>>(
      Xg, W1t, b1, btab, cnt, rowbase, list, wl, h, out);
  // W2 [E][D][C] f32 -> W2t [E][C][D] bf16
  transpose_conv_kernel<D_DIM, C_DIM><<<dim3(C_DIM / 256, D_DIM / 32, E_NUM), 512, 0, stream>>>(W2, W2t);
  gemm_rs_kernel<8, D_DIM, 2><<<MAXB * 8, 256, 0, stream>>>(
      h, W2t, b2, btab, cnt, rowbase, list, wl, h, out);
}